// Round 2
// baseline (423.321 us; speedup 1.0000x reference)
//
#include <hip/hip_runtime.h>
#include <hip/hip_bf16.h>

typedef __bf16 bf16;
typedef __bf16 bf16x4 __attribute__((ext_vector_type(4)));
typedef __bf16 bf16x8 __attribute__((ext_vector_type(8)));
typedef float f32x4 __attribute__((ext_vector_type(4)));

#define MFMA16(A, B, C) __builtin_amdgcn_mfma_f32_16x16x32_bf16((A), (B), (C), 0, 0, 0)

__device__ __forceinline__ void gload_lds16(const void* g, void* l) {
  __builtin_amdgcn_global_load_lds(
      (const __attribute__((address_space(1))) void*)g,
      (__attribute__((address_space(3))) void*)l, 16, 0, 0);
}

// ---------------- elementwise casts ----------------
__global__ void cast_f32_bf16_k(const float* __restrict__ src, bf16* __restrict__ dst, int n4) {
  int i = blockIdx.x * blockDim.x + threadIdx.x;
  if (i >= n4) return;
  float4 v = ((const float4*)src)[i];
  bf16x4 o = {(bf16)v.x, (bf16)v.y, (bf16)v.z, (bf16)v.w};
  ((bf16x4*)dst)[i] = o;
}

// ---------------- RoPE table ----------------
__global__ void rope_table_k(float* __restrict__ cosT, float* __restrict__ sinT) {
  int tid = blockIdx.x * blockDim.x + threadIdx.x;  // S*64
  int s = tid >> 6, i = tid & 63;
  float inv = exp2f(-(float)i * (19.931568569324174f / 64.0f));  // 1e6^(-i/64)
  float ang = (float)s * inv;
  cosT[tid] = cosf(ang);
  sinT[tid] = sinf(ang);
}

// ---------------- RoPE apply + reshape ----------------
__global__ void rope_q_k(const bf16* __restrict__ Qlin, const float* __restrict__ cosT,
                         const float* __restrict__ sinT, bf16* __restrict__ Qr) {
  int tid = blockIdx.x * blockDim.x + threadIdx.x;  // B*S*H*64
  int i = tid & 63;
  int h = (tid >> 6) & 15;
  int s = (tid >> 10) & 2047;
  int b = tid >> 21;
  const bf16* src = Qlin + ((size_t)(b * 2048 + s)) * 2048 + h * 128;
  float x1 = (float)src[i], x2 = (float)src[i + 64];
  float c = cosT[s * 64 + i], sn = sinT[s * 64 + i];
  bf16* dst = Qr + ((size_t)((b * 16 + h) * 2048 + s)) * 128;
  dst[i] = (bf16)(x1 * c - x2 * sn);
  dst[i + 64] = (bf16)(x2 * c + x1 * sn);
}

__global__ void rope_k_k(const bf16* __restrict__ KVlin, const float* __restrict__ cosT,
                         const float* __restrict__ sinT, bf16* __restrict__ Kr) {
  int tid = blockIdx.x * blockDim.x + threadIdx.x;  // B*S*KVH*64
  int i = tid & 63;
  int kvh = (tid >> 6) & 1;
  int s = (tid >> 7) & 2047;
  int b = tid >> 18;
  const bf16* src = KVlin + ((size_t)(b * 2048 + s)) * 512 + kvh * 128;
  float x1 = (float)src[i], x2 = (float)src[i + 64];
  float c = cosT[s * 64 + i], sn = sinT[s * 64 + i];
  bf16* dst = Kr + ((size_t)((b * 2 + kvh) * 2048 + s)) * 128;
  dst[i] = (bf16)(x1 * c - x2 * sn);
  dst[i + 64] = (bf16)(x2 * c + x1 * sn);
}

__global__ void v_tr_k(const bf16* __restrict__ KVlin, bf16* __restrict__ Vt) {
  int tid = blockIdx.x * blockDim.x + threadIdx.x;  // B*KVH*128*S
  int s = tid & 2047;
  int d = (tid >> 11) & 127;
  int kvh = (tid >> 18) & 1;
  int b = tid >> 19;
  Vt[tid] = KVlin[((size_t)(b * 2048 + s)) * 512 + 256 + kvh * 128 + d];
}

// ---------------- BT GEMM: C[M,N] = A[M,K] * B[N,K]^T (+bias) ----------------
template <typename OutT>
__global__ __launch_bounds__(256) void gemm_bt_k(
    const bf16* __restrict__ A, const bf16* __restrict__ Bm,
    const float* __restrict__ bias, OutT* __restrict__ C, int M, int N, int K) {
  __shared__ __align__(16) bf16 As[128 * 64];
  __shared__ __align__(16) bf16 Bs[128 * 64];
  const int tid = threadIdx.x;
  const int lane = tid & 63;
  const int w = tid >> 6;
  const int wr = w >> 1, wc = w & 1;
  const size_t bm = (size_t)blockIdx.y * 128;
  const size_t bn = (size_t)blockIdx.x * 128;
  const int l8r = lane >> 3, l8c = lane & 7;

  f32x4 acc[4][4] = {};

  for (int k0 = 0; k0 < K; k0 += 64) {
#pragma unroll
    for (int i = 0; i < 4; ++i) {
      int c = w * 4 + i;
      int row = c * 8 + l8r;
      gload_lds16(A + (bm + row) * (size_t)K + k0 + l8c * 8, (char*)As + c * 1024);
      gload_lds16(Bm + (bn + row) * (size_t)K + k0 + l8c * 8, (char*)Bs + c * 1024);
    }
    __syncthreads();
#pragma unroll
    for (int kk = 0; kk < 2; ++kk) {
      bf16x8 af[4], bfr[4];
#pragma unroll
      for (int mi = 0; mi < 4; ++mi) {
        int r = wr * 64 + mi * 16 + (lane & 15);
        af[mi] = *(const bf16x8*)(As + r * 64 + kk * 32 + (lane >> 4) * 8);
      }
#pragma unroll
      for (int ni = 0; ni < 4; ++ni) {
        int r = wc * 64 + ni * 16 + (lane & 15);
        bfr[ni] = *(const bf16x8*)(Bs + r * 64 + kk * 32 + (lane >> 4) * 8);
      }
#pragma unroll
      for (int mi = 0; mi < 4; ++mi)
#pragma unroll
        for (int ni = 0; ni < 4; ++ni)
          acc[mi][ni] = MFMA16(af[mi], bfr[ni], acc[mi][ni]);
    }
    __syncthreads();
  }
#pragma unroll
  for (int mi = 0; mi < 4; ++mi) {
#pragma unroll
    for (int ni = 0; ni < 4; ++ni) {
      int col = (int)bn + wc * 64 + ni * 16 + (lane & 15);
      float bv = bias ? bias[col] : 0.0f;
#pragma unroll
      for (int j = 0; j < 4; ++j) {
        size_t row = bm + wr * 64 + mi * 16 + (lane >> 4) * 4 + j;
        C[row * N + col] = (OutT)(acc[mi][ni][j] + bv);
      }
    }
  }
}

// ---------------- Flash attention v2 (causal, GQA 8:1) ----------------
// 32 q-rows per wave (mi=0,1), 128-row block-strips, pair (bp, 15-bp) -> 34 tiles/block.
// Double-buffered K/V LDS with prefetch-before-compute; 1 barrier per tile.
// exp2-domain online softmax with defer-max (THR 11.5 log2-units).
__global__ __launch_bounds__(256, 2) void attn_k(
    const bf16* __restrict__ Qr, const bf16* __restrict__ Kr, const bf16* __restrict__ Vt,
    bf16* __restrict__ O) {
  __shared__ __align__(16) bf16 Ks[2][64 * 128];   // 2 x 16KB, col-swizzled
  __shared__ __align__(16) bf16 Vs[2][128 * 64];   // 2 x 16KB, col-swizzled
  __shared__ __align__(16) bf16 Ps[4][32][72];     // per-wave P, +8 pad

  const int S = 2048;
  const int lane = threadIdx.x & 63;
  const int w = threadIdx.x >> 6;
  const int bh = blockIdx.y;
  const int b = bh >> 4, h = bh & 15;
  const int kvh = h >> 3;
  const bf16* Qbase = Qr + (size_t)bh * S * 128;
  const bf16* Kbase = Kr + (size_t)(b * 2 + kvh) * S * 128;
  const bf16* Vbase = Vt + (size_t)(b * 2 + kvh) * 128 * S;
  const float SCALE2 = 0.12751744f;  // (1/sqrt(128)) * log2(e)

  auto STAGE = [&](int bi, int t) {
#pragma unroll
    for (int i = 0; i < 4; ++i) {
      int c = w * 4 + i;
      {
        int row = c * 4 + (lane >> 4);
        int sc = ((lane & 15) ^ (row & 7)) * 8;
        gload_lds16(Kbase + (size_t)(t * 64 + row) * 128 + sc, (char*)&Ks[bi][0] + c * 1024);
      }
      {
        int row = c * 8 + (lane >> 3);
        int sc = ((lane & 7) ^ (row & 7)) * 8;
        gload_lds16(Vbase + (size_t)row * S + t * 64 + sc, (char*)&Vs[bi][0] + c * 1024);
      }
    }
  };

  for (int half = 0; half < 2; ++half) {
    const int bp = half ? (15 - blockIdx.x) : blockIdx.x;
    const int q0 = bp * 128 + w * 32;  // wave's first q-row
    bf16x8 qf[2][4];
#pragma unroll
    for (int mi = 0; mi < 2; ++mi)
#pragma unroll
      for (int kk = 0; kk < 4; ++kk)
        qf[mi][kk] = *(const bf16x8*)(Qbase + (size_t)(q0 + mi * 16 + (lane & 15)) * 128 +
                                      kk * 32 + (lane >> 4) * 8);

    float m_run[2][4], l_run[2][4];
    f32x4 o_acc[2][8] = {};
#pragma unroll
    for (int mi = 0; mi < 2; ++mi)
#pragma unroll
      for (int j = 0; j < 4; ++j) { m_run[mi][j] = -3.0e38f; l_run[mi][j] = 0.0f; }

    const int nt = 2 * bp + 2;
    const int tmw = 2 * bp + ((w >= 2) ? 1 : 0);  // last tile this wave computes

    STAGE(0, 0);
    __syncthreads();

    for (int t = 0; t < nt; ++t) {
      const int bi = t & 1;
      if (t + 1 < nt) STAGE(bi ^ 1, t + 1);

      if (t <= tmw) {
        // ---- QK^T ----
        f32x4 sacc[2][4] = {};
        __builtin_amdgcn_s_setprio(1);
#pragma unroll
        for (int kk = 0; kk < 4; ++kk) {
#pragma unroll
          for (int ni = 0; ni < 4; ++ni) {
            int n = ni * 16 + (lane & 15);
            int off = n * 256 + ((kk * 64 + (lane >> 4) * 16) ^ ((n & 7) << 4));
            bf16x8 kf = *(const bf16x8*)((const char*)&Ks[bi][0] + off);
            sacc[0][ni] = MFMA16(qf[0][kk], kf, sacc[0][ni]);
            sacc[1][ni] = MFMA16(qf[1][kk], kf, sacc[1][ni]);
          }
        }
        __builtin_amdgcn_s_setprio(0);

        // ---- mask + scale (log2 domain) + row max ----
        float tmax[2][4];
#pragma unroll
        for (int mi = 0; mi < 2; ++mi)
#pragma unroll
          for (int j = 0; j < 4; ++j) tmax[mi][j] = -3.0e38f;
#pragma unroll
        for (int mi = 0; mi < 2; ++mi) {
          int rb = q0 + mi * 16 + (lane >> 4) * 4;
#pragma unroll
          for (int ni = 0; ni < 4; ++ni) {
            int kc = t * 64 + ni * 16 + (lane & 15);
#pragma unroll
            for (int j = 0; j < 4; ++j) {
              float s = sacc[mi][ni][j] * SCALE2;
              s = (kc > rb + j) ? -3.0e38f : s;
              sacc[mi][ni][j] = s;
              tmax[mi][j] = fmaxf(tmax[mi][j], s);
            }
          }
        }
#pragma unroll
        for (int mi = 0; mi < 2; ++mi)
#pragma unroll
          for (int j = 0; j < 4; ++j) {
#pragma unroll
            for (int d = 1; d < 16; d <<= 1)
              tmax[mi][j] = fmaxf(tmax[mi][j], __shfl_xor(tmax[mi][j], d, 64));
          }

        // ---- defer-max rescale ----
        float growth = -3.0e38f;
#pragma unroll
        for (int mi = 0; mi < 2; ++mi)
#pragma unroll
          for (int j = 0; j < 4; ++j) growth = fmaxf(growth, tmax[mi][j] - m_run[mi][j]);
        if (__any(growth > 11.5f)) {
#pragma unroll
          for (int mi = 0; mi < 2; ++mi)
#pragma unroll
            for (int j = 0; j < 4; ++j) {
              float mnew = fmaxf(m_run[mi][j], tmax[mi][j]);
              float corr = exp2f(m_run[mi][j] - mnew);
              m_run[mi][j] = mnew;
              l_run[mi][j] *= corr;
#pragma unroll
              for (int n2 = 0; n2 < 8; ++n2) o_acc[mi][n2][j] *= corr;
            }
        }

        // ---- P = exp2(S - m), row sums, stage P to LDS ----
        float tsum[2][4] = {};
#pragma unroll
        for (int mi = 0; mi < 2; ++mi) {
#pragma unroll
          for (int ni = 0; ni < 4; ++ni) {
#pragma unroll
            for (int j = 0; j < 4; ++j) {
              float p = exp2f(sacc[mi][ni][j] - m_run[mi][j]);
              tsum[mi][j] += p;
              Ps[w][mi * 16 + (lane >> 4) * 4 + j][ni * 16 + (lane & 15)] = (bf16)p;
            }
          }
        }
#pragma unroll
        for (int mi = 0; mi < 2; ++mi)
#pragma unroll
          for (int j = 0; j < 4; ++j) {
#pragma unroll
            for (int d = 1; d < 16; d <<= 1) tsum[mi][j] += __shfl_xor(tsum[mi][j], d, 64);
            l_run[mi][j] += tsum[mi][j];
          }

        // ---- PV ----
        __builtin_amdgcn_s_setprio(1);
#pragma unroll
        for (int ks = 0; ks < 2; ++ks) {
          bf16x8 pf[2];
#pragma unroll
          for (int mi = 0; mi < 2; ++mi)
            pf[mi] = *(const bf16x8*)(&Ps[w][mi * 16 + (lane & 15)][ks * 32 + (lane >> 4) * 8]);
#pragma unroll
          for (int n2 = 0; n2 < 8; ++n2) {
            int n = n2 * 16 + (lane & 15);
            int off = n * 128 + ((ks * 64 + (lane >> 4) * 16) ^ ((n & 7) << 4));
            bf16x8 vf = *(const bf16x8*)((const char*)&Vs[bi][0] + off);
            o_acc[0][n2] = MFMA16(pf[0], vf, o_acc[0][n2]);
            o_acc[1][n2] = MFMA16(pf[1], vf, o_acc[1][n2]);
          }
        }
        __builtin_amdgcn_s_setprio(0);
      }
      __syncthreads();
    }

    // ---- epilogue ----
#pragma unroll
    for (int mi = 0; mi < 2; ++mi) {
      float rl[4];
#pragma unroll
      for (int j = 0; j < 4; ++j) rl[j] = 1.0f / l_run[mi][j];
#pragma unroll
      for (int n2 = 0; n2 < 8; ++n2) {
#pragma unroll
        for (int j = 0; j < 4; ++j) {
          int qr = q0 + mi * 16 + (lane >> 4) * 4 + j;
          O[((size_t)(b * S + qr)) * 2048 + h * 128 + n2 * 16 + (lane & 15)] =
              (bf16)(o_acc[mi][n2][j] * rl[j]);
        }
      }
    }
  }
}

// ---------------- launch ----------------
extern "C" void kernel_launch(void* const* d_in, const int* in_sizes, int n_in,
                              void* d_out, int out_size, void* d_ws, size_t ws_size,
                              hipStream_t stream) {
  const float* x   = (const float*)d_in[0];
  // d_in[1] = attn_mask (pure causal; applied analytically in attn_k)
  const float* Wq  = (const float*)d_in[2];
  const float* bq  = (const float*)d_in[3];
  const float* Wkv = (const float*)d_in[4];
  const float* bkv = (const float*)d_in[5];
  const float* Wo  = (const float*)d_in[6];
  float* out = (float*)d_out;
  char* ws = (char*)d_ws;

  bf16* xb    = (bf16*)(ws + 0);
  bf16* Wqb   = (bf16*)(ws + 16777216);
  bf16* Wkvb  = (bf16*)(ws + 25165824);
  bf16* Wob   = (bf16*)(ws + 27262976);
  bf16* Qlin  = (bf16*)(ws + 35651584);
  bf16* KVlin = (bf16*)(ws + 52428800);
  bf16* Qrr   = (bf16*)(ws + 56623104);
  bf16* Krr   = (bf16*)(ws + 73400320);
  bf16* Vtt   = (bf16*)(ws + 75497472);
  bf16* Oat   = (bf16*)(ws + 77594624);
  float* cosT = (float*)(ws + 94371840);
  float* sinT = (float*)(ws + 94896128);

  cast_f32_bf16_k<<<8192, 256, 0, stream>>>(x, xb, 2097152);
  cast_f32_bf16_k<<<4096, 256, 0, stream>>>(Wq, Wqb, 1048576);
  cast_f32_bf16_k<<<1024, 256, 0, stream>>>(Wkv, Wkvb, 262144);
  cast_f32_bf16_k<<<4096, 256, 0, stream>>>(Wo, Wob, 1048576);
  rope_table_k<<<512, 256, 0, stream>>>(cosT, sinT);

  gemm_bt_k<bf16><<<dim3(16, 32), 256, 0, stream>>>(xb, Wqb, bq, Qlin, 4096, 2048, 2048);
  gemm_bt_k<bf16><<<dim3(4, 32), 256, 0, stream>>>(xb, Wkvb, bkv, KVlin, 4096, 512, 2048);

  rope_q_k<<<16384, 256, 0, stream>>>(Qlin, cosT, sinT, Qrr);
  rope_k_k<<<2048, 256, 0, stream>>>(KVlin, cosT, sinT, Krr);
  v_tr_k<<<4096, 256, 0, stream>>>(KVlin, Vtt);

  attn_k<<<dim3(8, 32), 256, 0, stream>>>(Qrr, Krr, Vtt, Oat);

  gemm_bt_k<float><<<dim3(16, 32), 256, 0, stream>>>(Oat, Wob, nullptr, out, 4096, 2048, 2048);
}

// Round 4
// 380.705 us; speedup vs baseline: 1.1119x; 1.1119x over previous
//
#include <hip/hip_runtime.h>
#include <hip/hip_bf16.h>

typedef __bf16 bf16;
typedef __bf16 bf16x2 __attribute__((ext_vector_type(2)));
typedef __bf16 bf16x4 __attribute__((ext_vector_type(4)));
typedef __bf16 bf16x8 __attribute__((ext_vector_type(8)));
typedef float f32x4 __attribute__((ext_vector_type(4)));
typedef float f32x16 __attribute__((ext_vector_type(16)));

#define MFMA16(A, B, C) __builtin_amdgcn_mfma_f32_16x16x32_bf16((A), (B), (C), 0, 0, 0)
#define MFMA32(A, B, C) __builtin_amdgcn_mfma_f32_32x32x16_bf16((A), (B), (C), 0, 0, 0)

__device__ __forceinline__ void gload_lds16(const void* g, void* l) {
  __builtin_amdgcn_global_load_lds(
      (const __attribute__((address_space(1))) void*)g,
      (__attribute__((address_space(3))) void*)l, 16, 0, 0);
}

__device__ __forceinline__ unsigned pk2(float a, float b) {
  bf16x2 t = {(bf16)a, (bf16)b};
  return __builtin_bit_cast(unsigned, t);
}

// ---------------- elementwise casts ----------------
__global__ void cast_f32_bf16_k(const float* __restrict__ src, bf16* __restrict__ dst, int n4) {
  int i = blockIdx.x * blockDim.x + threadIdx.x;
  if (i >= n4) return;
  float4 v = ((const float4*)src)[i];
  bf16x4 o = {(bf16)v.x, (bf16)v.y, (bf16)v.z, (bf16)v.w};
  ((bf16x4*)dst)[i] = o;
}

// ---------------- RoPE table ----------------
__global__ void rope_table_k(float* __restrict__ cosT, float* __restrict__ sinT) {
  int tid = blockIdx.x * blockDim.x + threadIdx.x;  // S*64
  int s = tid >> 6, i = tid & 63;
  float inv = exp2f(-(float)i * (19.931568569324174f / 64.0f));  // 1e6^(-i/64)
  float ang = (float)s * inv;
  cosT[tid] = cosf(ang);
  sinT[tid] = sinf(ang);
}

// ---------------- RoPE apply + reshape ----------------
__global__ void rope_q_k(const bf16* __restrict__ Qlin, const float* __restrict__ cosT,
                         const float* __restrict__ sinT, bf16* __restrict__ Qr) {
  int tid = blockIdx.x * blockDim.x + threadIdx.x;  // B*S*H*64
  int i = tid & 63;
  int h = (tid >> 6) & 15;
  int s = (tid >> 10) & 2047;
  int b = tid >> 21;
  const bf16* src = Qlin + ((size_t)(b * 2048 + s)) * 2048 + h * 128;
  float x1 = (float)src[i], x2 = (float)src[i + 64];
  float c = cosT[s * 64 + i], sn = sinT[s * 64 + i];
  bf16* dst = Qr + ((size_t)((b * 16 + h) * 2048 + s)) * 128;
  dst[i] = (bf16)(x1 * c - x2 * sn);
  dst[i + 64] = (bf16)(x2 * c + x1 * sn);
}

__global__ void rope_k_k(const bf16* __restrict__ KVlin, const float* __restrict__ cosT,
                         const float* __restrict__ sinT, bf16* __restrict__ Kr) {
  int tid = blockIdx.x * blockDim.x + threadIdx.x;  // B*S*KVH*64
  int i = tid & 63;
  int kvh = (tid >> 6) & 1;
  int s = (tid >> 7) & 2047;
  int b = tid >> 18;
  const bf16* src = KVlin + ((size_t)(b * 2048 + s)) * 512 + kvh * 128;
  float x1 = (float)src[i], x2 = (float)src[i + 64];
  float c = cosT[s * 64 + i], sn = sinT[s * 64 + i];
  bf16* dst = Kr + ((size_t)((b * 2 + kvh) * 2048 + s)) * 128;
  dst[i] = (bf16)(x1 * c - x2 * sn);
  dst[i + 64] = (bf16)(x2 * c + x1 * sn);
}

__global__ void v_tr_k(const bf16* __restrict__ KVlin, bf16* __restrict__ Vt) {
  int tid = blockIdx.x * blockDim.x + threadIdx.x;  // B*KVH*128*S
  int s = tid & 2047;
  int d = (tid >> 11) & 127;
  int kvh = (tid >> 18) & 1;
  int b = tid >> 19;
  Vt[tid] = KVlin[((size_t)(b * 2048 + s)) * 512 + 256 + kvh * 128 + d];
}

// ---------------- BT GEMM: C[M,N] = A[M,K] * B[N,K]^T (+bias) ----------------
template <typename OutT>
__global__ __launch_bounds__(256) void gemm_bt_k(
    const bf16* __restrict__ A, const bf16* __restrict__ Bm,
    const float* __restrict__ bias, OutT* __restrict__ C, int M, int N, int K) {
  __shared__ __align__(16) bf16 As[128 * 64];
  __shared__ __align__(16) bf16 Bs[128 * 64];
  const int tid = threadIdx.x;
  const int lane = tid & 63;
  const int w = tid >> 6;
  const int wr = w >> 1, wc = w & 1;
  const size_t bm = (size_t)blockIdx.y * 128;
  const size_t bn = (size_t)blockIdx.x * 128;
  const int l8r = lane >> 3, l8c = lane & 7;

  f32x4 acc[4][4] = {};

  for (int k0 = 0; k0 < K; k0 += 64) {
#pragma unroll
    for (int i = 0; i < 4; ++i) {
      int c = w * 4 + i;
      int row = c * 8 + l8r;
      gload_lds16(A + (bm + row) * (size_t)K + k0 + l8c * 8, (char*)As + c * 1024);
      gload_lds16(Bm + (bn + row) * (size_t)K + k0 + l8c * 8, (char*)Bs + c * 1024);
    }
    __syncthreads();
#pragma unroll
    for (int kk = 0; kk < 2; ++kk) {
      bf16x8 af[4], bfr[4];
#pragma unroll
      for (int mi = 0; mi < 4; ++mi) {
        int r = wr * 64 + mi * 16 + (lane & 15);
        af[mi] = *(const bf16x8*)(As + r * 64 + kk * 32 + (lane >> 4) * 8);
      }
#pragma unroll
      for (int ni = 0; ni < 4; ++ni) {
        int r = wc * 64 + ni * 16 + (lane & 15);
        bfr[ni] = *(const bf16x8*)(Bs + r * 64 + kk * 32 + (lane >> 4) * 8);
      }
#pragma unroll
      for (int mi = 0; mi < 4; ++mi)
#pragma unroll
        for (int ni = 0; ni < 4; ++ni)
          acc[mi][ni] = MFMA16(af[mi], bfr[ni], acc[mi][ni]);
    }
    __syncthreads();
  }
#pragma unroll
  for (int mi = 0; mi < 4; ++mi) {
#pragma unroll
    for (int ni = 0; ni < 4; ++ni) {
      int col = (int)bn + wc * 64 + ni * 16 + (lane & 15);
      float bv = bias ? bias[col] : 0.0f;
#pragma unroll
      for (int j = 0; j < 4; ++j) {
        size_t row = bm + wr * 64 + mi * 16 + (lane >> 4) * 4 + j;
        C[row * N + col] = (OutT)(acc[mi][ni][j] + bv);
      }
    }
  }
}

// ---------------- Flash attention v3b: swapped-QK 32x32, in-register softmax ----------------
// Qr [B,H,S,128], Kr [B,KVH,S,128], Vt [B,KVH,128,S] -> O [B,S,H*128] (bf16)
// 4 warps x 32 q-rows = 128-row strip per block; KVBLK=64; dbuf K/V LDS (64KB, 2 blocks/CU).
// mfma(A=K,B=Q): lane holds P[.][q=lane&31]; softmax state per-lane (q=ql).
// PV output rows are q spread over regs (q_o(r) != ql) -> corr/rl redistributed via __shfl.
__global__ __launch_bounds__(256, 2) void attn_k(
    const bf16* __restrict__ Qr, const bf16* __restrict__ Kr, const bf16* __restrict__ Vt,
    bf16* __restrict__ O) {
  __shared__ __align__(16) bf16 Ks[2][64 * 128];  // [kv][d], 16B-granule XOR swizzle
  __shared__ __align__(16) bf16 Vs[2][128 * 64];  // [d][kv], 16B-granule XOR swizzle

  const int S = 2048;
  const int lane = threadIdx.x & 63;
  const int w = threadIdx.x >> 6;
  const int h = lane >> 5;   // wave half
  const int ql = lane & 31;  // this lane's q (col of swapped QK out)

  // (strip, 15-strip) pairing so co-resident blocks have equal work
  const int xx = blockIdx.x, yy = blockIdx.y;
  const int s4 = xx & 15;
  int strip, bh;
  if (yy < 8) { strip = s4;      bh = (xx >> 4) + 2 * yy; }
  else        { strip = 15 - s4; bh = (xx >> 4) + 2 * (yy - 8) + 16; }
  const int b = bh >> 4, head = bh & 15;
  const int kvh = head >> 3;
  const bf16* Qbase = Qr + (size_t)bh * S * 128;
  const bf16* Kbase = Kr + (size_t)(b * 2 + kvh) * S * 128;
  const bf16* Vbase = Vt + (size_t)(b * 2 + kvh) * 128 * S;
  const float SCALE2 = 0.12751744f;  // (1/sqrt(128)) * log2(e)

  auto STAGE = [&](int bi, int t) {
#pragma unroll
    for (int i = 0; i < 4; ++i) {
      int c = w * 4 + i;
      {
        int row = c * 4 + (lane >> 4);
        int g = (lane & 15) ^ (row & 7);
        gload_lds16(Kbase + (size_t)(t * 64 + row) * 128 + g * 8, (char*)&Ks[bi][0] + c * 1024);
      }
      {
        int row = c * 8 + (lane >> 3);
        int g = (lane & 7) ^ (row & 7);
        gload_lds16(Vbase + (size_t)row * S + t * 64 + g * 8, (char*)&Vs[bi][0] + c * 1024);
      }
    }
  };

  const int q_abs = strip * 128 + w * 32 + ql;
  bf16x8 qf[8];  // Q row q_abs, d = dc*16 + 8h + 0..7
#pragma unroll
  for (int dc = 0; dc < 8; ++dc)
    qf[dc] = *(const bf16x8*)(Qbase + (size_t)q_abs * 128 + dc * 16 + 8 * h);

  f32x16 o_acc[4] = {};
  float m_run = -3.0e38f, l_run = 0.0f;
  const int nt = 2 * strip + 2;
  const int tmw = 2 * strip + (w >> 1);  // last tile this warp needs

  STAGE(0, 0);
  __syncthreads();

  for (int t = 0; t < nt; ++t) {
    const int bi = t & 1;
    if (t + 1 < nt) STAGE(bi ^ 1, t + 1);

    if (t <= tmw) {
      const char* kb = (const char*)&Ks[bi][0];
      const char* vb = (const char*)&Vs[bi][0];

      // ---- QK^T (swapped): sa0 = S[kv 0..31][q], sa1 = S[kv 32..63][q] ----
      f32x16 sa0 = {}, sa1 = {};
      __builtin_amdgcn_s_setprio(1);
#pragma unroll
      for (int dc = 0; dc < 8; ++dc) {
        int off = ql * 256 + (((2 * dc + h) ^ (ql & 7)) << 4);
        bf16x8 k0 = *(const bf16x8*)(kb + off);
        bf16x8 k1 = *(const bf16x8*)(kb + off + 32 * 256);
        sa0 = MFMA32(k0, qf[dc], sa0);
        sa1 = MFMA32(k1, qf[dc], sa1);
      }
      __builtin_amdgcn_s_setprio(0);

      // ---- scale + causal mask + row max (row = q = ql, in-lane) ----
      const bool full = (t * 64 + 63 <= strip * 128 + w * 32);
      float pm = -3.0e38f;
      if (full) {
#pragma unroll
        for (int r = 0; r < 16; ++r) {
          sa0[r] *= SCALE2;
          sa1[r] *= SCALE2;
          pm = fmaxf(pm, fmaxf(sa0[r], sa1[r]));
        }
      } else {
#pragma unroll
        for (int r = 0; r < 16; ++r) {
          int kvr = t * 64 + (r & 3) + 8 * (r >> 2) + 4 * h;
          float v0 = sa0[r] * SCALE2, v1 = sa1[r] * SCALE2;
          v0 = (kvr > q_abs) ? -3.0e38f : v0;
          v1 = (kvr + 32 > q_abs) ? -3.0e38f : v1;
          sa0[r] = v0;
          sa1[r] = v1;
          pm = fmaxf(pm, fmaxf(v0, v1));
        }
      }
      pm = fmaxf(pm, __shfl_xor(pm, 32, 64));

      // ---- defer-max rescale (T13); corr is per-q=ql, o_acc rows are q_o(r):
      // redistribute with __shfl (lanes ql and ql+32 hold identical state) ----
      if (__any(pm - m_run > 11.5f)) {
        float mnew = fmaxf(m_run, pm);
        float corr = exp2f(m_run - mnew);
        m_run = mnew;
        l_run *= corr;
#pragma unroll
        for (int r = 0; r < 16; ++r) {
          float corr_r = __shfl(corr, (r & 3) + 8 * (r >> 2) + 4 * h, 64);
#pragma unroll
          for (int dt = 0; dt < 4; ++dt) o_acc[dt][r] *= corr_r;
        }
      }

      // ---- P = exp2(S - m), row sum (per-lane, q = ql) ----
      float ts = 0.0f;
#pragma unroll
      for (int r = 0; r < 16; ++r) {
        float p0 = exp2f(sa0[r] - m_run);
        float p1 = exp2f(sa1[r] - m_run);
        sa0[r] = p0;
        sa1[r] = p1;
        ts += p0 + p1;
      }
      ts += __shfl_xor(ts, 32, 64);
      l_run += ts;

      // ---- pack P -> PV A-frags: pa[c] = P[q=ql][kv = c*16 + 8h + 0..7] ----
      bf16x8 pa[4];
#pragma unroll
      for (int c = 0; c < 4; ++c) {
        const f32x16& A = (c < 2) ? sa0 : sa1;
        const int base = (c & 1) * 8;
        unsigned lo0 = pk2(A[base + 0], A[base + 1]);
        unsigned lo1 = pk2(A[base + 2], A[base + 3]);
        unsigned hi0 = pk2(A[base + 4], A[base + 5]);
        unsigned hi1 = pk2(A[base + 6], A[base + 7]);
        unsigned k0 = h ? hi0 : lo0, k1 = h ? hi1 : lo1;
        unsigned s0 = h ? lo0 : hi0, s1 = h ? lo1 : hi1;
        unsigned r0 = __shfl_xor(s0, 32, 64);
        unsigned r1 = __shfl_xor(s1, 32, 64);
        uint4 wd;
        wd.x = h ? r0 : k0;
        wd.y = h ? r1 : k1;
        wd.z = h ? k0 : r0;
        wd.w = h ? k1 : r1;
        pa[c] = __builtin_bit_cast(bf16x8, wd);
      }

      // ---- PV: o_acc[dt] += P[q][kv-chunk c] * V[kv][d = dt*32 + ql] ----
      __builtin_amdgcn_s_setprio(1);
#pragma unroll
      for (int c = 0; c < 4; ++c) {
#pragma unroll
        for (int dt = 0; dt < 4; ++dt) {
          int rd = dt * 32 + ql;
          int off = rd * 128 + (((2 * c + h) ^ (ql & 7)) << 4);
          bf16x8 vf = *(const bf16x8*)(vb + off);
          o_acc[dt] = MFMA32(pa[c], vf, o_acc[dt]);
        }
      }
      __builtin_amdgcn_s_setprio(0);
    }
    __syncthreads();
  }

  // ---- epilogue: normalize each o_acc row by ITS q's 1/l via shfl ----
  float rl = 1.0f / l_run;
  bf16* Ob = O + ((size_t)b * S) * 2048 + head * 128;
#pragma unroll
  for (int r = 0; r < 16; ++r) {
    int q_o = (r & 3) + 8 * (r >> 2) + 4 * h;
    float rl_r = __shfl(rl, q_o, 64);
    int qrow = strip * 128 + w * 32 + q_o;
#pragma unroll
    for (int dt = 0; dt < 4; ++dt) {
      Ob[(size_t)qrow * 2048 + dt * 32 + ql] = (bf16)(o_acc[dt][r] * rl_r);
    }
  }
}

// ---------------- launch ----------------
extern "C" void kernel_launch(void* const* d_in, const int* in_sizes, int n_in,
                              void* d_out, int out_size, void* d_ws, size_t ws_size,
                              hipStream_t stream) {
  const float* x   = (const float*)d_in[0];
  // d_in[1] = attn_mask (pure causal; applied analytically in attn_k)
  const float* Wq  = (const float*)d_in[2];
  const float* bq  = (const float*)d_in[3];
  const float* Wkv = (const float*)d_in[4];
  const float* bkv = (const float*)d_in[5];
  const float* Wo  = (const float*)d_in[6];
  float* out = (float*)d_out;
  char* ws = (char*)d_ws;

  bf16* xb    = (bf16*)(ws + 0);
  bf16* Wqb   = (bf16*)(ws + 16777216);
  bf16* Wkvb  = (bf16*)(ws + 25165824);
  bf16* Wob   = (bf16*)(ws + 27262976);
  bf16* Qlin  = (bf16*)(ws + 35651584);
  bf16* KVlin = (bf16*)(ws + 52428800);
  bf16* Qrr   = (bf16*)(ws + 56623104);
  bf16* Krr   = (bf16*)(ws + 73400320);
  bf16* Vtt   = (bf16*)(ws + 75497472);
  bf16* Oat   = (bf16*)(ws + 77594624);
  float* cosT = (float*)(ws + 94371840);
  float* sinT = (float*)(ws + 94896128);

  cast_f32_bf16_k<<<8192, 256, 0, stream>>>(x, xb, 2097152);
  cast_f32_bf16_k<<<4096, 256, 0, stream>>>(Wq, Wqb, 1048576);
  cast_f32_bf16_k<<<1024, 256, 0, stream>>>(Wkv, Wkvb, 262144);
  cast_f32_bf16_k<<<4096, 256, 0, stream>>>(Wo, Wob, 1048576);
  rope_table_k<<<512, 256, 0, stream>>>(cosT, sinT);

  gemm_bt_k<bf16><<<dim3(16, 32), 256, 0, stream>>>(xb, Wqb, bq, Qlin, 4096, 2048, 2048);
  gemm_bt_k<bf16><<<dim3(4, 32), 256, 0, stream>>>(xb, Wkvb, bkv, KVlin, 4096, 512, 2048);

  rope_q_k<<<16384, 256, 0, stream>>>(Qlin, cosT, sinT, Qrr);
  rope_k_k<<<2048, 256, 0, stream>>>(KVlin, cosT, sinT, Krr);
  v_tr_k<<<4096, 256, 0, stream>>>(KVlin, Vtt);

  attn_k<<<dim3(32, 16), 256, 0, stream>>>(Qrr, Krr, Vtt, Oat);

  gemm_bt_k<float><<<dim3(16, 32), 256, 0, stream>>>(Oat, Wob, nullptr, out, 4096, 2048, 2048);
}